// Round 3
// baseline (65.918 us; speedup 1.0000x reference)
//
#include <hip/hip_runtime.h>

// ---------------------------------------------------------------------------
// Joint network: y = relu(f@W1t^T + g@W1p^T + (b1t+b1p)) @ W2^T + b2
// N=32768, K1=1344 (1024 f + 320 g), J=512, KOUT=29. fp32 in/out, bf16 MFMA.
// R3: 2-phase barrier-paired K-step (T3), depth-2 B prefetch w/ counted
//     vmcnt(6) (T4), setprio around MFMA clusters (T5). B triple-buffered.
// ---------------------------------------------------------------------------

typedef float  f32x4  __attribute__((ext_vector_type(4)));
typedef short  s16x8  __attribute__((ext_vector_type(8)));   // 8 bf16 = 4 VGPRs

#define N_ROWS   32768
#define K1       1344
#define NKS      42            // K1 / 32
#define JDIM     512
#define KOUT     29

#define WC_ELEMS   (NKS * 4 * 512 * 8)   // 688128 bf16: [ks][kc][j][8]
#define W2C_ELEMS  (64 * 32 * 8)         // 16384 bf16:  [jc][kout][8]

#define VMCNT(n)   asm volatile("s_waitcnt vmcnt(" #n ")" ::: "memory")
#define LGKM0()    asm volatile("s_waitcnt lgkmcnt(0)" ::: "memory")
#define SBAR()     __builtin_amdgcn_s_barrier()
#define PRIO(n)    __builtin_amdgcn_s_setprio(n)

typedef const __attribute__((address_space(1))) unsigned int* gp_t;
typedef __attribute__((address_space(3))) unsigned int* lp_t;

static __device__ __forceinline__ void gls16(const void* g, void* l) {
  __builtin_amdgcn_global_load_lds((gp_t)g, (lp_t)l, 16, 0, 0);
}

static __device__ __forceinline__ unsigned short f2bf(float x) {
  union { float f; unsigned u; } v; v.f = x;
  unsigned r = v.u + 0x7fffu + ((v.u >> 16) & 1u);   // RNE
  return (unsigned short)(r >> 16);
}

static __device__ __forceinline__ s16x8 cvt8(const f32x4 a, const f32x4 b) {
  s16x8 r;
  r[0] = (short)f2bf(a[0]); r[1] = (short)f2bf(a[1]);
  r[2] = (short)f2bf(a[2]); r[3] = (short)f2bf(a[3]);
  r[4] = (short)f2bf(b[0]); r[5] = (short)f2bf(b[1]);
  r[6] = (short)f2bf(b[2]); r[7] = (short)f2bf(b[3]);
  return r;
}

// ---------------------------------------------------------------------------
__global__ __launch_bounds__(512) void prep_kernel(
    const float* __restrict__ W1t, const float* __restrict__ b1t,
    const float* __restrict__ W1p, const float* __restrict__ b1p,
    const float* __restrict__ W2,  const float* __restrict__ b2,
    unsigned short* __restrict__ Wc, unsigned short* __restrict__ W2c,
    float* __restrict__ bc, float* __restrict__ b2c) {
  int idx = blockIdx.x * 512 + threadIdx.x;
  if (idx < WC_ELEMS) {
    int e  = idx & 7;
    int j  = (idx >> 3) & 511;
    int kc = (idx >> 12) & 3;
    int ks = idx >> 14;
    int c  = ks * 32 + kc * 8 + e;
    float v = (c < 1024) ? W1t[j * 1024 + c] : W1p[j * 320 + (c - 1024)];
    Wc[idx] = f2bf(v);
  }
  if (idx < W2C_ELEMS) {
    int e  = idx & 7;
    int ko = (idx >> 3) & 31;
    int jc = idx >> 8;
    int j  = jc * 8 + e;
    float v = (ko < KOUT) ? W2[ko * 512 + j] : 0.0f;
    W2c[idx] = f2bf(v);
  }
  if (idx < 512) bc[idx]  = b1t[idx] + b1p[idx];
  if (idx < 32)  b2c[idx] = (idx < KOUT) ? b2[idx] : 0.0f;
}

// ---------------------------------------------------------------------------
// Main fused kernel. 256 blocks x 512 threads (8 waves, 2M x 4N wave grid).
// Block tile 128 x 512 (full J). Wave tile 64 x 128.
// LDS: A dbuf [2][4kc][128row][8] @0       (16 KB, XOR-swizzled)
//      B tri  [3][4kc][512 j][8]  @16384   (96 KB, gls-linear, depth-2 pf)
//      phase2 h-half               @0      (64 KB, aliases A/B0/B1)
//      W2 LDS [64jc][32ko][8]     @114688  (32 KB, persistent, gls-staged)
// Total 144 KB static -> 1 block/CU.
// ---------------------------------------------------------------------------
__global__ __launch_bounds__(512, 2) void joint_kernel(
    const float* __restrict__ f, const float* __restrict__ g,
    const unsigned short* __restrict__ Wc, const unsigned short* __restrict__ W2c,
    const float* __restrict__ bc, const float* __restrict__ b2c,
    float* __restrict__ out) {
  __shared__ __align__(16) char smem[147456];

  const int tid = threadIdx.x;
  const int l   = tid & 63;
  const int w   = tid >> 6;          // wave 0..7
  const int wm  = w >> 2;            // 0..1  (rows:  wm*64)
  const int wn  = w & 3;             // 0..3  (cols:  wn*128)
  const int m0  = blockIdx.x * 128;

  // phase-1 A staging mapping: row = tid>>2, kc = tid&3 (128B/row coalesced)
  const int srow = tid >> 2;
  const int skc  = tid & 3;
  const float* fRow = f + (size_t)(m0 + srow) * 1024;
  const float* gRow = g + (size_t)(m0 + srow) * 320;
  const unsigned a_wr = (unsigned)(skc * 2048 + ((srow * 16) ^ (skc << 5)));

  // fragment read offsets
  const int kcg = l >> 4;            // 0..3
  const int lc  = l & 15;
  const unsigned a_rd = (unsigned)(kcg * 2048 + ((lc * 16) ^ (kcg << 5)) + wm * 1024);
  const unsigned b_rd = (unsigned)(16384 + kcg * 8192 + lc * 16 + wn * 2048);

  f32x4 acc[4][8];
#pragma unroll
  for (int m = 0; m < 4; m++)
#pragma unroll
    for (int n = 0; n < 8; n++) acc[m][n] = (f32x4)(0.0f);

  f32x4 paA0, paA1, paB0, paB1;      // A prefetch ring (depth 2)

#define ISSUE_A(dst0, dst1, T) {                                            \
    int c_ = (T) * 32 + skc * 8;                                            \
    const float* p_ = (c_ < 1024) ? (fRow + c_) : (gRow + (c_ - 1024));     \
    dst0 = *(const f32x4*)p_;                                               \
    dst1 = *(const f32x4*)(p_ + 4);                                         \
  }

  // B staging halves: direct global->LDS, 2 x 16B per thread per half.
#define GLS_B_H0(T, NXTB) {                                                 \
    const char* bs_ = (const char*)Wc + (size_t)(T) * 32768 + tid * 16;     \
    char* bd_ = smem + 16384 + (NXTB) * 32768 + tid * 16;                   \
    gls16(bs_,          bd_);                                               \
    gls16(bs_ +  8192,  bd_ +  8192);                                       \
  }
#define GLS_B_H1(T, NXTB) {                                                 \
    const char* bs_ = (const char*)Wc + (size_t)(T) * 32768 + tid * 16;     \
    char* bd_ = smem + 16384 + (NXTB) * 32768 + tid * 16;                   \
    gls16(bs_ + 16384,  bd_ + 16384);                                       \
    gls16(bs_ + 24576,  bd_ + 24576);                                       \
  }

#define WRITE_A(AB, s0, s1) {                                               \
    *(s16x8*)(smem + (AB) * 8192 + a_wr) = cvt8(s0, s1);                    \
  }

  // One K-step, two barrier-paired phases of 16 MFMA each.
  // T: K-step index. CURB: B buf (T%3). NXTB: (T+2)%3. ABUF: T&1.
  // WRB: (T+1)&1. pi: regs receiving A(T+2). pw: regs holding A(T+1).
#define K_ITER(T, CURB, NXTB, ABUF, WRB, pi0, pi1, pw0, pw1, DO_PRE, DO_WR) { \
    s16x8 af[4]; s16x8 bq[4];                                               \
    _Pragma("unroll")                                                       \
    for (int m = 0; m < 4; m++)                                             \
      af[m] = *(const s16x8*)(smem + (ABUF) * 8192 + a_rd + m * 256);       \
    _Pragma("unroll")                                                       \
    for (int n = 0; n < 4; n++)                                             \
      bq[n] = *(const s16x8*)(smem + (CURB) * 32768 + b_rd + n * 256);      \
    if (DO_PRE) { GLS_B_H0(T + 2, NXTB); }                                  \
    SBAR();                                                                 \
    LGKM0();                                                                \
    PRIO(1);                                                                \
    _Pragma("unroll")                                                       \
    for (int m = 0; m < 4; m++)                                             \
      _Pragma("unroll")                                                     \
      for (int n = 0; n < 4; n++)                                           \
        acc[m][n] = __builtin_amdgcn_mfma_f32_16x16x32_bf16(                \
            af[m], bq[n], acc[m][n], 0, 0, 0);                              \
    PRIO(0);                                                                \
    SBAR();                                                                 \
    _Pragma("unroll")                                                       \
    for (int n = 0; n < 4; n++)                                             \
      bq[n] = *(const s16x8*)(smem + (CURB) * 32768 + b_rd + (4 + n) * 256);\
    if (DO_PRE) { GLS_B_H1(T + 2, NXTB); ISSUE_A(pi0, pi1, T + 2); }        \
    if (DO_WR)  { WRITE_A(WRB, pw0, pw1); }                                 \
    VMCNT(6);                                                               \
    SBAR();                                                                 \
    LGKM0();                                                                \
    PRIO(1);                                                                \
    _Pragma("unroll")                                                       \
    for (int m = 0; m < 4; m++)                                             \
      _Pragma("unroll")                                                     \
      for (int n = 0; n < 4; n++)                                           \
        acc[m][4 + n] = __builtin_amdgcn_mfma_f32_16x16x32_bf16(            \
            af[m], bq[n], acc[m][4 + n], 0, 0, 0);                          \
    PRIO(0);                                                                \
    SBAR();                                                                 \
  }

  // ---- prologue: W2, B(0)->buf0, B(1)->buf1, A(0), A(1); write A(0) ----
  {
    const char* wsrc = (const char*)W2c + tid * 16;
    char* wdst = smem + 114688 + tid * 16;
    gls16(wsrc,          wdst);
    gls16(wsrc +  8192,  wdst +  8192);
    gls16(wsrc + 16384,  wdst + 16384);
    gls16(wsrc + 24576,  wdst + 24576);
  }
  GLS_B_H0(0, 0); GLS_B_H1(0, 0);
  GLS_B_H0(1, 1); GLS_B_H1(1, 1);
  ISSUE_A(paA0, paA1, 0);
  ISSUE_A(paB0, paB1, 1);
  WRITE_A(0, paA0, paA1);     // implicit vmcnt(2): drains W2, B0, B1, A0
  LGKM0();
  SBAR();

  // ---- main K loop: 42 steps = 6 x unroll-6 + peeled 6-step tail ----
  for (int tb = 0; tb < 36; tb += 6) {
    K_ITER(tb + 0, 0, 2, 0, 1, paA0, paA1, paB0, paB1, 1, 1);
    K_ITER(tb + 1, 1, 0, 1, 0, paB0, paB1, paA0, paA1, 1, 1);
    K_ITER(tb + 2, 2, 1, 0, 1, paA0, paA1, paB0, paB1, 1, 1);
    K_ITER(tb + 3, 0, 2, 1, 0, paB0, paB1, paA0, paA1, 1, 1);
    K_ITER(tb + 4, 1, 0, 0, 1, paA0, paA1, paB0, paB1, 1, 1);
    K_ITER(tb + 5, 2, 1, 1, 0, paB0, paB1, paA0, paA1, 1, 1);
  }
  K_ITER(36, 0, 2, 0, 1, paA0, paA1, paB0, paB1, 1, 1);
  K_ITER(37, 1, 0, 1, 0, paB0, paB1, paA0, paA1, 1, 1);
  K_ITER(38, 2, 1, 0, 1, paA0, paA1, paB0, paB1, 1, 1);
  K_ITER(39, 0, 2, 1, 0, paB0, paB1, paA0, paA1, 1, 1);
  K_ITER(40, 1, 0, 0, 1, paA0, paA1, paB0, paB1, 0, 1);
  K_ITER(41, 2, 1, 1, 0, paB0, paB1, paA0, paA1, 0, 0);

  // ---- phase 2: y = relu(h+bias) @ W2^T + b2, h kept on-chip ----
  float bias[8];
#pragma unroll
  for (int n = 0; n < 8; n++) bias[n] = bc[wn * 128 + n * 16 + lc];

  f32x4 acc2[2];
  acc2[0] = (f32x4)(0.0f);
  acc2[1] = (f32x4)(0.0f);

  const unsigned h_rd  = (unsigned)(kcg * 2048 + (w * 16 + lc) * 16);
  const unsigned w2_rd = (unsigned)(114688 + kcg * 512 + lc * 16);
  const unsigned h_wr  = (unsigned)((((wn & 1) * 16) + (lc >> 3)) * 2048 +
                                    (wm * 64 + kcg * 4) * 16 + (l & 7) * 2);
  const int myp = (w >> 1) & 1;

#pragma unroll
  for (int p = 0; p < 2; p++) {
    __syncthreads();                 // h buffer free
    if (myp == p) {
#pragma unroll
      for (int n = 0; n < 8; n++)
#pragma unroll
        for (int m = 0; m < 4; m++)
#pragma unroll
          for (int r = 0; r < 4; r++) {
            float v = acc[m][n][r] + bias[n];
            v = fmaxf(v, 0.0f);
            *(unsigned short*)(smem + h_wr + n * 4096 + m * 256 + r * 16) = f2bf(v);
          }
    }
    __syncthreads();
#pragma unroll
    for (int ks2 = 0; ks2 < 8; ks2++) {
      s16x8 hf = *(const s16x8*)(smem + h_rd + ks2 * 8192);
      s16x8 w0 = *(const s16x8*)(smem + w2_rd + p * 16384 + ks2 * 2048);
      s16x8 w1 = *(const s16x8*)(smem + w2_rd + p * 16384 + ks2 * 2048 + 256);
      acc2[0] = __builtin_amdgcn_mfma_f32_16x16x32_bf16(hf, w0, acc2[0], 0, 0, 0);
      acc2[1] = __builtin_amdgcn_mfma_f32_16x16x32_bf16(hf, w1, acc2[1], 0, 0, 0);
    }
  }

  // ---- epilogue: +b2, store 29 of 32 cols ----
  const float bb0 = b2c[lc];
  const float bb1 = b2c[16 + lc];
  const int orow0 = m0 + w * 16 + kcg * 4;
#pragma unroll
  for (int r = 0; r < 4; r++) {
    const size_t row = (size_t)(orow0 + r);
    out[row * KOUT + lc] = acc2[0][r] + bb0;
    if (lc < KOUT - 16) out[row * KOUT + 16 + lc] = acc2[1][r] + bb1;
  }

#undef ISSUE_A
#undef GLS_B_H0
#undef GLS_B_H1
#undef WRITE_A
#undef K_ITER
}

// ---------------------------------------------------------------------------
extern "C" void kernel_launch(void* const* d_in, const int* in_sizes, int n_in,
                              void* d_out, int out_size, void* d_ws, size_t ws_size,
                              hipStream_t stream) {
  const float* f   = (const float*)d_in[0];
  const float* g   = (const float*)d_in[1];
  const float* W1t = (const float*)d_in[2];
  const float* b1t = (const float*)d_in[3];
  const float* W1p = (const float*)d_in[4];
  const float* b1p = (const float*)d_in[5];
  const float* W2  = (const float*)d_in[6];
  const float* b2  = (const float*)d_in[7];
  float* out = (float*)d_out;

  unsigned short* Wc  = (unsigned short*)d_ws;
  unsigned short* W2c = Wc + WC_ELEMS;
  float* bcp  = (float*)(W2c + W2C_ELEMS);
  float* b2cp = bcp + 512;

  prep_kernel<<<WC_ELEMS / 512, 512, 0, stream>>>(W1t, b1t, W1p, b1p, W2, b2,
                                                  Wc, W2c, bcp, b2cp);
  joint_kernel<<<N_ROWS / 128, 512, 0, stream>>>(f, g, Wc, W2c, bcp, b2cp, out);
}

// Round 4
// 65.602 us; speedup vs baseline: 1.0048x; 1.0048x over previous
//
#include <hip/hip_runtime.h>

// ---------------------------------------------------------------------------
// Joint network: y = relu(f@W1t^T + g@W1p^T + (b1t+b1p)) @ W2^T + b2
// N=32768, K1=1344 (1024 f + 320 g), J=512, KOUT=29. fp32 in/out, bf16 MFMA.
// R4: B weights read directly global->registers (L2-resident, no LDS, no
//     barriers); A reg-staged depth-3 into LDS dbuf; ONE barrier per K-step.
// ---------------------------------------------------------------------------

typedef float  f32x4  __attribute__((ext_vector_type(4)));
typedef short  s16x8  __attribute__((ext_vector_type(8)));   // 8 bf16 = 4 VGPRs

#define N_ROWS   32768
#define NKS      42            // K1 / 32
#define KOUT     29

#define WC_ELEMS   (NKS * 4 * 512 * 8)   // 688128 bf16: [ks][kc][j][8]
#define W2C_ELEMS  (64 * 32 * 8)         // 16384 bf16:  [jc][kout][8]

#define LGKM0()    asm volatile("s_waitcnt lgkmcnt(0)" ::: "memory")
#define SBAR()     __builtin_amdgcn_s_barrier()
#define PRIO(n)    __builtin_amdgcn_s_setprio(n)

typedef const __attribute__((address_space(1))) unsigned int* gp_t;
typedef __attribute__((address_space(3))) unsigned int* lp_t;

static __device__ __forceinline__ void gls16(const void* g, void* l) {
  __builtin_amdgcn_global_load_lds((gp_t)g, (lp_t)l, 16, 0, 0);
}

static __device__ __forceinline__ unsigned short f2bf(float x) {
  union { float f; unsigned u; } v; v.f = x;
  unsigned r = v.u + 0x7fffu + ((v.u >> 16) & 1u);   // RNE
  return (unsigned short)(r >> 16);
}

static __device__ __forceinline__ s16x8 cvt8(const f32x4 a, const f32x4 b) {
  s16x8 r;
  r[0] = (short)f2bf(a[0]); r[1] = (short)f2bf(a[1]);
  r[2] = (short)f2bf(a[2]); r[3] = (short)f2bf(a[3]);
  r[4] = (short)f2bf(b[0]); r[5] = (short)f2bf(b[1]);
  r[6] = (short)f2bf(b[2]); r[7] = (short)f2bf(b[3]);
  return r;
}

// ---------------------------------------------------------------------------
__global__ __launch_bounds__(512) void prep_kernel(
    const float* __restrict__ W1t, const float* __restrict__ b1t,
    const float* __restrict__ W1p, const float* __restrict__ b1p,
    const float* __restrict__ W2,  const float* __restrict__ b2,
    unsigned short* __restrict__ Wc, unsigned short* __restrict__ W2c,
    float* __restrict__ bc, float* __restrict__ b2c) {
  int idx = blockIdx.x * 512 + threadIdx.x;
  if (idx < WC_ELEMS) {
    int e  = idx & 7;
    int j  = (idx >> 3) & 511;
    int kc = (idx >> 12) & 3;
    int ks = idx >> 14;
    int c  = ks * 32 + kc * 8 + e;
    float v = (c < 1024) ? W1t[j * 1024 + c] : W1p[j * 320 + (c - 1024)];
    Wc[idx] = f2bf(v);
  }
  if (idx < W2C_ELEMS) {
    int e  = idx & 7;
    int ko = (idx >> 3) & 31;
    int jc = idx >> 8;
    int j  = jc * 8 + e;
    float v = (ko < KOUT) ? W2[ko * 512 + j] : 0.0f;
    W2c[idx] = f2bf(v);
  }
  if (idx < 512) bc[idx]  = b1t[idx] + b1p[idx];
  if (idx < 32)  b2c[idx] = (idx < KOUT) ? b2[idx] : 0.0f;
}

// ---------------------------------------------------------------------------
// Main fused kernel. 256 blocks x 512 threads (8 waves, 2M x 4N wave grid).
// Block tile 128 x 512 (full J). Wave tile 64 x 128.
// LDS: A dbuf [2][4kc][128row][8] @0      (16 KB, XOR-swizzled)
//      phase2 h-half               @0     (64 KB, aliases A after K loop)
//      W2 LDS [64jc][32ko][8]     @65536  (32 KB, persistent, gls-staged)
// Total 96 KB. B never touches LDS: global->reg, depth-1 ping-pong.
// ---------------------------------------------------------------------------
__global__ __launch_bounds__(512, 2) void joint_kernel(
    const float* __restrict__ f, const float* __restrict__ g,
    const unsigned short* __restrict__ Wc, const unsigned short* __restrict__ W2c,
    const float* __restrict__ bc, const float* __restrict__ b2c,
    float* __restrict__ out) {
  __shared__ __align__(16) char smem[98304];

  const int tid = threadIdx.x;
  const int l   = tid & 63;
  const int w   = tid >> 6;          // wave 0..7
  const int wm  = w >> 2;            // 0..1  (rows:  wm*64)
  const int wn  = w & 3;             // 0..3  (cols:  wn*128)
  const int m0  = blockIdx.x * 128;

  // A staging mapping: row = tid>>2, kc = tid&3 (128B/row coalesced)
  const int srow = tid >> 2;
  const int skc  = tid & 3;
  const float* fRow = f + (size_t)(m0 + srow) * 1024;
  const float* gRow = g + (size_t)(m0 + srow) * 320;
  const unsigned a_wr = (unsigned)(skc * 2048 + ((srow * 16) ^ (skc << 5)));

  // fragment read offsets
  const int kcg = l >> 4;            // 0..3
  const int lc  = l & 15;
  const unsigned a_rd = (unsigned)(kcg * 2048 + ((lc * 16) ^ (kcg << 5)) + wm * 1024);
  // B global fragment offset: element (j = wn*128 + n*16 + lc, k-chunk kcg)
  const unsigned b_goff = (unsigned)(kcg * 8192 + wn * 2048 + lc * 16);
  const char* Wb = (const char*)Wc + b_goff;

  f32x4 acc[4][8];
#pragma unroll
  for (int m = 0; m < 4; m++)
#pragma unroll
    for (int n = 0; n < 8; n++) acc[m][n] = (f32x4)(0.0f);

  f32x4 pa0_0, pa0_1, pa1_0, pa1_1, pa2_0, pa2_1;  // A prefetch ring depth 3
  s16x8 bqX[8], bqY[8];                            // B ping-pong (reg frags)

#define ISSUE_A(d0, d1, T) {                                                \
    int c_ = (T) * 32 + skc * 8;                                            \
    const float* p_ = (c_ < 1024) ? (fRow + c_) : (gRow + (c_ - 1024));     \
    d0 = *(const f32x4*)p_;                                                 \
    d1 = *(const f32x4*)(p_ + 4);                                           \
  }

#define ISSUE_B(dst, T) {                                                   \
    const char* bs_ = Wb + (size_t)(T) * 32768;                             \
    _Pragma("unroll")                                                       \
    for (int n_ = 0; n_ < 8; n_++)                                          \
      dst[n_] = *(const s16x8*)(bs_ + n_ * 256);                            \
  }

#define WRITE_A(AB, s0, s1) {                                               \
    *(s16x8*)(smem + (AB) * 8192 + a_wr) = cvt8(s0, s1);                    \
  }

  // One K-step. Loads stay in flight across the barrier (reg dests =>
  // compiler emits exact counted vmcnt before each use).
#define K_STEP(T, ABUF, WRB, CUR, NXT, pl0, pl1, pw0, pw1, PRE_B, PRE_A, WR) { \
    if (PRE_B) { ISSUE_B(NXT, (T) + 1); }                                   \
    if (PRE_A) { ISSUE_A(pl0, pl1, (T) + 3); }                              \
    s16x8 af[4];                                                            \
    _Pragma("unroll")                                                       \
    for (int m = 0; m < 4; m++)                                             \
      af[m] = *(const s16x8*)(smem + (ABUF) * 8192 + a_rd + m * 256);       \
    PRIO(1);                                                                \
    _Pragma("unroll")                                                       \
    for (int m = 0; m < 4; m++)                                             \
      _Pragma("unroll")                                                     \
      for (int n = 0; n < 8; n++)                                           \
        acc[m][n] = __builtin_amdgcn_mfma_f32_16x16x32_bf16(                \
            af[m], CUR[n], acc[m][n], 0, 0, 0);                             \
    PRIO(0);                                                                \
    if (WR) { WRITE_A(WRB, pw0, pw1); }                                     \
    LGKM0();                                                                \
    SBAR();                                                                 \
  }

  // ---- prologue: W2 gls, B(0)->bqX, A(0..2) regs, write A(0) ----
  {
    const char* wsrc = (const char*)W2c + tid * 16;
    char* wdst = smem + 65536 + tid * 16;
    gls16(wsrc,          wdst);
    gls16(wsrc +  8192,  wdst +  8192);
    gls16(wsrc + 16384,  wdst + 16384);
    gls16(wsrc + 24576,  wdst + 24576);
  }
  ISSUE_B(bqX, 0);
  ISSUE_A(pa0_0, pa0_1, 0);
  ISSUE_A(pa1_0, pa1_1, 1);
  ISSUE_A(pa2_0, pa2_1, 2);
  WRITE_A(0, pa0_0, pa0_1);      // compiler waits exactly for A(0)
  LGKM0();
  SBAR();

  // Step T: ABUF=T&1, WRB=(T+1)&1, CUR=bq[T&1], issue B(T+1)->bq[~T&1],
  // issue A(T+3)->pa[T%3], write A(T+1) from pa[(T+1)%3].
  // Unroll 6 = lcm(2,3) for static indices.
  for (int tb = 0; tb < 36; tb += 6) {
    K_STEP(tb + 0, 0, 1, bqX, bqY, pa0_0, pa0_1, pa1_0, pa1_1, 1, 1, 1);
    K_STEP(tb + 1, 1, 0, bqY, bqX, pa1_0, pa1_1, pa2_0, pa2_1, 1, 1, 1);
    K_STEP(tb + 2, 0, 1, bqX, bqY, pa2_0, pa2_1, pa0_0, pa0_1, 1, 1, 1);
    K_STEP(tb + 3, 1, 0, bqY, bqX, pa0_0, pa0_1, pa1_0, pa1_1, 1, 1, 1);
    K_STEP(tb + 4, 0, 1, bqX, bqY, pa1_0, pa1_1, pa2_0, pa2_1, 1, 1, 1);
    K_STEP(tb + 5, 1, 0, bqY, bqX, pa2_0, pa2_1, pa0_0, pa0_1, 1, 1, 1);
  }
  // tail: T=36..41 (A issues stop at T=38: A(41) is last)
  K_STEP(36, 0, 1, bqX, bqY, pa0_0, pa0_1, pa1_0, pa1_1, 1, 1, 1);
  K_STEP(37, 1, 0, bqY, bqX, pa1_0, pa1_1, pa2_0, pa2_1, 1, 1, 1);
  K_STEP(38, 0, 1, bqX, bqY, pa2_0, pa2_1, pa0_0, pa0_1, 1, 1, 1);
  K_STEP(39, 1, 0, bqY, bqX, pa0_0, pa0_1, pa1_0, pa1_1, 1, 0, 1);
  K_STEP(40, 0, 1, bqX, bqY, pa0_0, pa0_1, pa2_0, pa2_1, 1, 0, 1);
  K_STEP(41, 1, 0, bqY, bqX, pa0_0, pa0_1, pa0_0, pa0_1, 0, 0, 0);

  // ---- phase 2: y = relu(h+bias) @ W2^T + b2, h kept on-chip ----
  float bias[8];
#pragma unroll
  for (int n = 0; n < 8; n++) bias[n] = bc[wn * 128 + n * 16 + lc];

  f32x4 acc2[2];
  acc2[0] = (f32x4)(0.0f);
  acc2[1] = (f32x4)(0.0f);

  const unsigned h_rd  = (unsigned)(kcg * 2048 + (w * 16 + lc) * 16);
  const unsigned w2_rd = (unsigned)(65536 + kcg * 512 + lc * 16);
  const unsigned h_wr  = (unsigned)((((wn & 1) * 16) + (lc >> 3)) * 2048 +
                                    (wm * 64 + kcg * 4) * 16 + (l & 7) * 2);
  const int myp = (w >> 1) & 1;

#pragma unroll
  for (int p = 0; p < 2; p++) {
    __syncthreads();                 // h buffer free (also drains W2 gls)
    if (myp == p) {
#pragma unroll
      for (int n = 0; n < 8; n++)
#pragma unroll
        for (int m = 0; m < 4; m++)
#pragma unroll
          for (int r = 0; r < 4; r++) {
            float v = acc[m][n][r] + bias[n];
            v = fmaxf(v, 0.0f);
            *(unsigned short*)(smem + h_wr + n * 4096 + m * 256 + r * 16) = f2bf(v);
          }
    }
    __syncthreads();
#pragma unroll
    for (int ks2 = 0; ks2 < 8; ks2++) {
      s16x8 hf = *(const s16x8*)(smem + h_rd + ks2 * 8192);
      s16x8 w0 = *(const s16x8*)(smem + w2_rd + p * 16384 + ks2 * 2048);
      s16x8 w1 = *(const s16x8*)(smem + w2_rd + p * 16384 + ks2 * 2048 + 256);
      acc2[0] = __builtin_amdgcn_mfma_f32_16x16x32_bf16(hf, w0, acc2[0], 0, 0, 0);
      acc2[1] = __builtin_amdgcn_mfma_f32_16x16x32_bf16(hf, w1, acc2[1], 0, 0, 0);
    }
  }

  // ---- epilogue: +b2, store 29 of 32 cols ----
  const float bb0 = b2c[lc];
  const float bb1 = b2c[16 + lc];
  const int orow0 = m0 + w * 16 + kcg * 4;
#pragma unroll
  for (int r = 0; r < 4; r++) {
    const size_t row = (size_t)(orow0 + r);
    out[row * KOUT + lc] = acc2[0][r] + bb0;
    if (lc < KOUT - 16) out[row * KOUT + 16 + lc] = acc2[1][r] + bb1;
  }

#undef ISSUE_A
#undef ISSUE_B
#undef WRITE_A
#undef K_STEP
}

// ---------------------------------------------------------------------------
extern "C" void kernel_launch(void* const* d_in, const int* in_sizes, int n_in,
                              void* d_out, int out_size, void* d_ws, size_t ws_size,
                              hipStream_t stream) {
  const float* f   = (const float*)d_in[0];
  const float* g   = (const float*)d_in[1];
  const float* W1t = (const float*)d_in[2];
  const float* b1t = (const float*)d_in[3];
  const float* W1p = (const float*)d_in[4];
  const float* b1p = (const float*)d_in[5];
  const float* W2  = (const float*)d_in[6];
  const float* b2  = (const float*)d_in[7];
  float* out = (float*)d_out;

  unsigned short* Wc  = (unsigned short*)d_ws;
  unsigned short* W2c = Wc + WC_ELEMS;
  float* bcp  = (float*)(W2c + W2C_ELEMS);
  float* b2cp = bcp + 512;

  prep_kernel<<<WC_ELEMS / 512, 512, 0, stream>>>(W1t, b1t, W1p, b1p, W2, b2,
                                                  Wc, W2c, bcp, b2cp);
  joint_kernel<<<N_ROWS / 128, 512, 0, stream>>>(f, g, Wc, W2c, bcp, b2cp, out);
}

// Round 5
// 58.498 us; speedup vs baseline: 1.1269x; 1.1215x over previous
//
#include <hip/hip_runtime.h>

// ---------------------------------------------------------------------------
// Joint network: y = relu(f@W1t^T + g@W1p^T + (b1t+b1p)) @ W2^T + b2
// N=32768, K1=1344 (1024 f + 320 g), J=512, KOUT=29. fp32 in/out, bf16 MFMA.
// R5: occupancy fix. BM=64, grid=512, 2 blocks/CU (16 waves/CU, 4/SIMD).
//     Wave tile 64x64 (acc=64 VGPR), LDS 48KB, one barrier/step.
// ---------------------------------------------------------------------------

typedef float  f32x4  __attribute__((ext_vector_type(4)));
typedef short  s16x8  __attribute__((ext_vector_type(8)));   // 8 bf16
typedef short  s16x4  __attribute__((ext_vector_type(4)));   // 4 bf16

#define N_ROWS   32768
#define NKS      42            // K1 / 32
#define KOUT     29

#define WC_ELEMS   (NKS * 4 * 512 * 8)   // 688128 bf16: [ks][kc][j][8]
#define W2C_ELEMS  (64 * 32 * 8)         // 16384 bf16:  [jc][kout32][8]

#define LGKM0()    asm volatile("s_waitcnt lgkmcnt(0)" ::: "memory")
#define SBAR()     __builtin_amdgcn_s_barrier()
#define PRIO(n)    __builtin_amdgcn_s_setprio(n)

typedef const __attribute__((address_space(1))) unsigned int* gp_t;
typedef __attribute__((address_space(3))) unsigned int* lp_t;

static __device__ __forceinline__ void gls16(const void* g, void* l) {
  __builtin_amdgcn_global_load_lds((gp_t)g, (lp_t)l, 16, 0, 0);
}

static __device__ __forceinline__ unsigned short f2bf(float x) {
  union { float f; unsigned u; } v; v.f = x;
  unsigned r = v.u + 0x7fffu + ((v.u >> 16) & 1u);   // RNE
  return (unsigned short)(r >> 16);
}

// ---------------------------------------------------------------------------
__global__ __launch_bounds__(512) void prep_kernel(
    const float* __restrict__ W1t, const float* __restrict__ b1t,
    const float* __restrict__ W1p, const float* __restrict__ b1p,
    const float* __restrict__ W2,  const float* __restrict__ b2,
    unsigned short* __restrict__ Wc, unsigned short* __restrict__ W2c,
    float* __restrict__ bc, float* __restrict__ b2c) {
  int idx = blockIdx.x * 512 + threadIdx.x;
  if (idx < WC_ELEMS) {
    int e  = idx & 7;
    int j  = (idx >> 3) & 511;
    int kc = (idx >> 12) & 3;
    int ks = idx >> 14;
    int c  = ks * 32 + kc * 8 + e;
    float v = (c < 1024) ? W1t[j * 1024 + c] : W1p[j * 320 + (c - 1024)];
    Wc[idx] = f2bf(v);
  }
  if (idx < W2C_ELEMS) {
    int e  = idx & 7;
    int ko = (idx >> 3) & 31;
    int jc = idx >> 8;
    int j  = jc * 8 + e;
    float v = (ko < KOUT) ? W2[ko * 512 + j] : 0.0f;
    W2c[idx] = f2bf(v);
  }
  if (idx < 512) bc[idx]  = b1t[idx] + b1p[idx];
  if (idx < 32)  b2c[idx] = (idx < KOUT) ? b2[idx] : 0.0f;
}

// ---------------------------------------------------------------------------
// Main fused kernel. 512 blocks x 512 threads (8 waves). Block tile 64 x 512.
// Wave w computes 64 rows x cols [w*64, w*64+64) : 4m x 4n of 16x16 tiles.
// LDS: A dbuf [2][4kc][64row][8] @0      (8 KB, XOR-swizzled)
//      phase2 h-chunk [16pl][64r][8]@0   (16 KB, aliases A after K loop)
//      W2 [64jc][32ko][8]         @16384 (32 KB, persistent, gls-staged)
// Total 48 KB -> with <=128 VGPR: 2 blocks/CU (16 waves/CU).
// B never touches LDS: global->reg per step (L2-resident, 1.4 MB).
// ---------------------------------------------------------------------------
__global__ __launch_bounds__(512, 4) void joint_kernel(
    const float* __restrict__ f, const float* __restrict__ g,
    const unsigned short* __restrict__ Wc, const unsigned short* __restrict__ W2c,
    const float* __restrict__ bc, const float* __restrict__ b2c,
    float* __restrict__ out) {
  __shared__ __align__(16) char smem[49152];

  const int tid = threadIdx.x;
  const int l   = tid & 63;
  const int w   = tid >> 6;          // wave 0..7 (col slice w*64)
  const int m0  = blockIdx.x * 64;

  // A staging mapping: row = tid>>3 (64), kq = tid&7 (8 x 4 fp32 = 32 k)
  const int srow = tid >> 3;
  const int kq   = tid & 7;
  const char* fA = (const char*)(f + (size_t)(m0 + srow) * 1024 + kq * 4);
  const char* gA = (const char*)(g + (size_t)(m0 + srow) * 320  + kq * 4);
  const int kcpl = kq >> 1;
  const unsigned a_wr = (unsigned)(kcpl * 1024 +
      ((srow * 16 + (kq & 1) * 8) ^ (kcpl << 5)));

  // fragment read offsets
  const int kcg = l >> 4;            // 0..3
  const int lc  = l & 15;
  const unsigned a_rd = (unsigned)(kcg * 1024 + ((lc * 16) ^ (kcg << 5)));
  // B global base: j = w*64 + n*16 + lc, k-chunk kcg
  const char* WbT = (const char*)Wc + kcg * 8192 + (w * 64 + lc) * 16;

  f32x4 acc[4][4];
#pragma unroll
  for (int m = 0; m < 4; m++)
#pragma unroll
    for (int n = 0; n < 4; n++) acc[m][n] = (f32x4)(0.0f);

  f32x4 rawE, rawO;   // A prefetch ping-pong: issueSet(T) = (T even ? E : O)

#define STAGE_A(BUF, SRCREG) {                                              \
    s16x4 hv;                                                               \
    hv[0] = (short)f2bf(SRCREG[0]); hv[1] = (short)f2bf(SRCREG[1]);         \
    hv[2] = (short)f2bf(SRCREG[2]); hv[3] = (short)f2bf(SRCREG[3]);         \
    *(s16x4*)(smem + (BUF) * 4096 + a_wr) = hv;                             \
  }

  // One K-step: load B(T) frags, read A frags, issue A(T+2), 16 MFMA,
  // stage A(T+1) from CONS, one barrier. Counted vmcnt is compiler-exact
  // (register destinations) -- A(T+2)/B stay in flight across the barrier.
#define K_STEP(T, CONS, ISSU, DO_A, ASRC, DO_WR) {                          \
    s16x8 bq[4];                                                            \
    const char* pb_ = WbT + (size_t)(T) * 32768;                            \
    _Pragma("unroll")                                                       \
    for (int n = 0; n < 4; n++) bq[n] = *(const s16x8*)(pb_ + n * 256);     \
    s16x8 af[4];                                                            \
    _Pragma("unroll")                                                       \
    for (int m = 0; m < 4; m++)                                             \
      af[m] = *(const s16x8*)(smem + ((T) & 1) * 4096 + a_rd + m * 256);    \
    if (DO_A) { ISSU = *(const f32x4*)(ASRC); }                             \
    PRIO(1);                                                                \
    _Pragma("unroll")                                                       \
    for (int m = 0; m < 4; m++)                                             \
      _Pragma("unroll")                                                     \
      for (int n = 0; n < 4; n++)                                           \
        acc[m][n] = __builtin_amdgcn_mfma_f32_16x16x32_bf16(                \
            af[m], bq[n], acc[m][n], 0, 0, 0);                              \
    PRIO(0);                                                                \
    if (DO_WR) { STAGE_A(((T) + 1) & 1, CONS); }                            \
    LGKM0();                                                                \
    SBAR();                                                                 \
  }

  // ---- prologue: W2 -> LDS (gls), A(0)->rawE, A(1)->rawO, stage A(0) ----
  {
    const char* wsrc = (const char*)W2c + tid * 16;
    char* wdst = smem + 16384 + tid * 16;
    gls16(wsrc,          wdst);
    gls16(wsrc +  8192,  wdst +  8192);
    gls16(wsrc + 16384,  wdst + 16384);
    gls16(wsrc + 24576,  wdst + 24576);
  }
  rawE = *(const f32x4*)(fA);          // A(0)
  rawO = *(const f32x4*)(fA + 128);    // A(1)
  STAGE_A(0, rawE);                    // waits exactly for rawE
  LGKM0();
  SBAR();

  // ---- K loop: T=0..41. A(T+2) src: f for T<=29, g for 30<=T<=39 ----
  for (int t2 = 0; t2 < 30; t2 += 2) {
    K_STEP(t2,     rawO, rawE, 1, fA + (t2 + 2) * 128, 1);
    K_STEP(t2 + 1, rawE, rawO, 1, fA + (t2 + 3) * 128, 1);
  }
  K_STEP(30, rawO, rawE, 1, gA,       1);
  K_STEP(31, rawE, rawO, 1, gA + 128, 1);
  for (int t2 = 32; t2 < 40; t2 += 2) {
    K_STEP(t2,     rawO, rawE, 1, gA + (t2 - 30) * 128, 1);
    K_STEP(t2 + 1, rawE, rawO, 1, gA + (t2 - 29) * 128, 1);
  }
  K_STEP(40, rawO, rawE, 0, fA, 1);    // stages A(41) from rawO
  K_STEP(41, rawE, rawO, 0, fA, 0);

  // ---- phase 2: y = relu(h+bias) @ W2^T + b2, h streamed in 4 chunks ----
  // Chunk p covers j in [p*128, (p+1)*128) -> written by waves w = 2p, 2p+1.
  // All 8 waves then MFMA: wave w owns y-tile (rows (w&3)*16.., ko (w>>2)*16..).
  float bias[4];
#pragma unroll
  for (int n = 0; n < 4; n++) bias[n] = bc[w * 64 + n * 16 + lc];

  f32x4 acc2 = (f32x4)(0.0f);
  const int myw = w >> 1;
  const int ko  = (w >> 2) * 16 + lc;
  const unsigned h_rdrow = (unsigned)(((w & 3) * 16 + lc) * 16);

#pragma unroll
  for (int p = 0; p < 4; p++) {
    __syncthreads();                 // chunk region free (also drains W2 gls)
    if (myw == p) {
#pragma unroll
      for (int n = 0; n < 4; n++) {
        const int jrel  = (w & 1) * 64 + n * 16 + lc;
        const int plane = jrel >> 3;
        const unsigned wbase = (unsigned)(plane * 1024 + (jrel & 7) * 2);
        const unsigned wswz  = (unsigned)((plane & 3) << 5);
#pragma unroll
        for (int m = 0; m < 4; m++)
#pragma unroll
          for (int r = 0; r < 4; r++) {
            float v = fmaxf(acc[m][n][r] + bias[n], 0.0f);
            const unsigned rowh = (unsigned)(m * 16 + kcg * 4 + r);
            *(unsigned short*)(smem + plane * 1024 +
                ((rowh * 16 + (jrel & 7) * 2) ^ wswz)) = f2bf(v);
            (void)wbase;
          }
      }
    }
    __syncthreads();
#pragma unroll
    for (int ks2 = 0; ks2 < 4; ks2++) {
      const int plane = ks2 * 4 + kcg;
      s16x8 hf = *(const s16x8*)(smem + plane * 1024 +
                                 (h_rdrow ^ ((unsigned)(plane & 3) << 5)));
      s16x8 wf = *(const s16x8*)(smem + 16384 + (p * 16 + plane) * 512 + ko * 16);
      acc2 = __builtin_amdgcn_mfma_f32_16x16x32_bf16(hf, wf, acc2, 0, 0, 0);
    }
  }

  // ---- epilogue: +b2, store (29 of 32 cols) ----
  if (ko < KOUT) {
    const float bb = b2c[ko];
    const int orow0 = m0 + (w & 3) * 16 + kcg * 4;
#pragma unroll
    for (int r = 0; r < 4; r++)
      out[(size_t)(orow0 + r) * KOUT + ko] = acc2[r] + bb;
  }

#undef STAGE_A
#undef K_STEP
}

// ---------------------------------------------------------------------------
extern "C" void kernel_launch(void* const* d_in, const int* in_sizes, int n_in,
                              void* d_out, int out_size, void* d_ws, size_t ws_size,
                              hipStream_t stream) {
  const float* f   = (const float*)d_in[0];
  const float* g   = (const float*)d_in[1];
  const float* W1t = (const float*)d_in[2];
  const float* b1t = (const float*)d_in[3];
  const float* W1p = (const float*)d_in[4];
  const float* b1p = (const float*)d_in[5];
  const float* W2  = (const float*)d_in[6];
  const float* b2  = (const float*)d_in[7];
  float* out = (float*)d_out;

  unsigned short* Wc  = (unsigned short*)d_ws;
  unsigned short* W2c = Wc + WC_ELEMS;
  float* bcp  = (float*)(W2c + W2C_ELEMS);
  float* b2cp = bcp + 512;

  prep_kernel<<<WC_ELEMS / 512, 512, 0, stream>>>(W1t, b1t, W1p, b1p, W2, b2,
                                                  Wc, W2c, bcp, b2cp);
  joint_kernel<<<N_ROWS / 64, 512, 0, stream>>>(f, g, Wc, W2c, bcp, b2cp, out);
}